// Round 8
// baseline (4688.202 us; speedup 1.0000x reference)
//
#include <hip/hip_runtime.h>

#define LAYERS 4
#define BATCH  64
#define SEQ    256
#define HID    1024
#define NGRP   8          // (layer, team) groups
#define GBLK   32         // blocks per group
#define SLAB   32768      // halfs per h slab: 32 rows x 1024 cols

typedef _Float16 half8  __attribute__((ext_vector_type(8)));
typedef _Float16 half2v __attribute__((ext_vector_type(2)));
typedef float    f32x4  __attribute__((ext_vector_type(4)));
typedef float    f32x2  __attribute__((ext_vector_type(2)));
typedef unsigned long long u64;

__device__ __forceinline__ float sig_(float x) { return 1.0f / (1.0f + __expf(-x)); }
__device__ __forceinline__ float th_(float x)  { return 2.0f / (1.0f + __expf(-2.0f * x)) - 1.0f; }

// sc1 store: relaxed agent-scope atomic -> write-through to Infinity Cache.
__device__ __forceinline__ void llc_store_h2(_Float16* p, half2v v) {
    union { half2v h; unsigned u; } cv; cv.h = v;
    __hip_atomic_store((unsigned*)p, cv.u, __ATOMIC_RELAXED, __HIP_MEMORY_SCOPE_AGENT);
}

// Sync state. loc[] counters are used with L2-executing atomics (no sc1) by
// same-XCD blocks only; glb[] counters use agent-scope (IF) atomics.
struct SyncSt {
    int      loc[NGRP][16];
    int      glb[NGRP][16];
    unsigned xmask[NGRP][16];
    int      xcnt[NGRP][16];
};

__global__ void k_bias(const float* __restrict__ bih, const float* __restrict__ bhh,
                       float* __restrict__ bias) {
    int i = blockIdx.x * blockDim.x + threadIdx.x;
    if (i < LAYERS * 4 * HID) bias[i] = bih[i] + bhh[i];
}

// Weights fp32 -> f16, fragment order for the 32-col/32-row geometry:
// c = lane6 | kc3 | nt3 | q2 | jblk5 | kh1 | l2  (LSB first)
// W row = l*4H + (nt>>1)*H + jblk*32 + (nt&1)*16 + (lane&15)
// W col = q*256 + kc*32 + (lane>>4)*8
__global__ void k_packw(const float* __restrict__ wih32, const float* __restrict__ whh32,
                        _Float16* __restrict__ wpack) {
    unsigned c = blockIdx.x * blockDim.x + threadIdx.x;   // < 2^22
    int lane = c & 63, kc = (c >> 6) & 7, nt = (c >> 9) & 7, q = (c >> 12) & 3;
    int jblk = (c >> 14) & 31, kh = (c >> 19) & 1, l = (int)(c >> 20);
    const float* src = (kh ? whh32 : wih32)
        + ((size_t)l * 4 * HID + (size_t)(nt >> 1) * HID + jblk * 32 + (nt & 1) * 16 + (lane & 15)) * HID
        + q * 256 + kc * 32 + (lane >> 4) * 8;
    f32x4 a = *(const f32x4*)src;
    f32x4 b = *(const f32x4*)(src + 4);
    half8 d;
    d[0]=(_Float16)a[0]; d[1]=(_Float16)a[1]; d[2]=(_Float16)a[2]; d[3]=(_Float16)a[3];
    d[4]=(_Float16)b[0]; d[5]=(_Float16)b[1]; d[6]=(_Float16)b[2]; d[7]=(_Float16)b[3];
    *(half8*)(wpack + (size_t)c * 8) = d;
}

// x fp32 [B,T,H] -> f16 fragment order: c = lane6 | i5 | mt1 | team1 | t8
// m = team*32 + mt*16 + (lane&15); k = i*32 + (lane>>4)*8
__global__ void k_packx(const float* __restrict__ x32, _Float16* __restrict__ xpack) {
    unsigned c = blockIdx.x * blockDim.x + threadIdx.x;   // < 2^21
    int lane = c & 63, i = (c >> 6) & 31, mt = (c >> 11) & 1, team = (c >> 12) & 1;
    int t = (int)(c >> 13);
    int m = team * 32 + mt * 16 + (lane & 15);
    int k = i * 32 + (lane >> 4) * 8;
    const float* src = x32 + ((size_t)m * SEQ + t) * HID + k;
    f32x4 a = *(const f32x4*)src;
    f32x4 b = *(const f32x4*)(src + 4);
    half8 d;
    d[0]=(_Float16)a[0]; d[1]=(_Float16)a[1]; d[2]=(_Float16)a[2]; d[3]=(_Float16)a[3];
    d[4]=(_Float16)b[0]; d[5]=(_Float16)b[1]; d[6]=(_Float16)b[2]; d[7]=(_Float16)b[3];
    *(half8*)(xpack + (size_t)c * 8) = d;
}

__device__ __forceinline__ size_t hslot(int t, int l, int team) {
    return (size_t)1 + (((size_t)t * LAYERS + l) << 1) + team;
}

// ---------------------------------------------------------------------------
// Persistent kernel, XCD-local recurrence:
//  - 256 blocks x 512 thr; group g = bid&7 = (layer<<1)|team (bid%8 == XCD by
//    the observed dispatch mapping, VERIFIED at runtime via HW_REG_XCC_ID).
//  - weights in registers (256/lane); c-state + bias in LDS.
//  - own-layer h exchange (critical path): plain stores into a 2-parity local
//    ring (lands in the group's XCD L2), readers use asm sc0 loads (bypass L1,
//    L2-hit), publish/poll via L2-executing global_atomic_add (no sc1).
//  - cross-layer h: sc1 write-once hfull + agent counters (r4-r7 proven);
//    its IF latency is a constant per LAYER, amortized over the sequence.
//  - if a group's blocks span >1 XCD: that group falls back to the IF path.
// ---------------------------------------------------------------------------
__global__ __launch_bounds__(512, 2) void k_persist(
        const _Float16* __restrict__ xpack,
        const _Float16* __restrict__ wpack,
        const float*    __restrict__ bih,
        const float*    __restrict__ bhh,
        _Float16*       __restrict__ hfull,   // write-once slabs (IF, sc1)
        _Float16*       __restrict__ hloc,    // [NGRP][2 parity][SLAB] local ring
        SyncSt*         __restrict__ sy,
        float*          __restrict__ out)
{
    const int g     = blockIdx.x & 7;
    const int jblk  = blockIdx.x >> 3;        // 0..31
    const int layer = g >> 1;
    const int team  = g & 1;
    const int j0    = jblk << 5;
    const int tid   = threadIdx.x;
    const int wave  = tid >> 6;
    const int q     = wave & 3;
    const int kh    = wave >> 2;              // 0: x-side, 1: h-side
    const int lane  = tid & 63;
    const int nl    = lane & 15;
    const int quad  = lane >> 4;

    __shared__ __align__(16) float gplane[4][32][132];  // [q][row][gatecol pad]
    __shared__ __align__(16) float cbuf[32][34];
    __shared__ __align__(16) float gbias[4][32];
    __shared__ int sflag;

    for (int i = tid; i < 32 * 34; i += 512) ((float*)cbuf)[i] = 0.0f;
    if (tid < 128) {
        int gg = tid >> 5, col = tid & 31;
        size_t bidx = (size_t)layer * 4 * HID + (size_t)gg * HID + j0 + col;
        gbias[gg][col] = bih[bidx] + bhh[bidx];
    }

    // ---- XCD identification (hwreg 20 = HW_REG_XCC_ID on gfx94x/950) ----
    if (tid == 0) {
        unsigned xcc;
        asm volatile("s_getreg_b32 %0, hwreg(20, 0, 32)" : "=s"(xcc));
        xcc &= 7u;
        __hip_atomic_fetch_or(&sy->xmask[g][0], 1u << xcc,
                              __ATOMIC_RELAXED, __HIP_MEMORY_SCOPE_AGENT);
        __hip_atomic_fetch_add(&sy->xcnt[g][0], 1,
                               __ATOMIC_RELAXED, __HIP_MEMORY_SCOPE_AGENT);
    }

    // ---- weights -> registers (8 nt x 8 kc x half8 = 256 regs/lane) ----
    const _Float16* Wp = wpack
        + ((((size_t)(layer * 2 + kh) * 32 + jblk) * 4 + q) * 64) * 512
        + (size_t)lane * 8;
    half8 wreg[8][8];
    #pragma unroll
    for (int nt = 0; nt < 8; ++nt)
        #pragma unroll
        for (int kc = 0; kc < 8; ++kc)
            wreg[nt][kc] = *(const half8*)(Wp + (nt * 8 + kc) * 512);

    if (tid == 0) {
        while (__hip_atomic_load(&sy->xcnt[g][0], __ATOMIC_RELAXED,
                                 __HIP_MEMORY_SCOPE_AGENT) < GBLK)
            __builtin_amdgcn_s_sleep(1);
        unsigned m = __hip_atomic_load(&sy->xmask[g][0], __ATOMIC_RELAXED,
                                       __HIP_MEMORY_SCOPE_AGENT);
        sflag = (__popc(m) == 1) ? 1 : 0;
    }
    __syncthreads();
    const bool locok = (sflag != 0);
    const bool lastlayer = (layer == LAYERS - 1);

    for (int t = 0; t < SEQ; ++t) {
        f32x4 acc[2][8];   // [mt][nt]
        #pragma unroll
        for (int mt = 0; mt < 2; ++mt)
            #pragma unroll
            for (int nt = 0; nt < 8; ++nt) acc[mt][nt] = (f32x4){0, 0, 0, 0};

        if (kh == 0) {
            // ---- x-side: wait for layer below (slack-amortized, IF path) ----
            if (lane == 0 && layer > 0) {
                const int tgt = GBLK * (t + 1);
                while (__hip_atomic_load(&sy->glb[g - 2][0], __ATOMIC_RELAXED,
                                         __HIP_MEMORY_SCOPE_AGENT) < tgt)
                    __builtin_amdgcn_s_sleep(1);
            }
            __builtin_amdgcn_sched_barrier(0);
            asm volatile("" ::: "memory");

            const _Float16* Ab = (layer == 0)
                ? xpack + ((size_t)t * 2 + team) * SLAB
                : hfull + hslot(t, layer - 1, team) * SLAB;
            const _Float16* Ap = Ab + (size_t)q * 4096 + (size_t)lane * 8;

            #pragma unroll
            for (int kc = 0; kc < 8; ++kc) {
                half8 a0 = *(const half8*)(Ap + kc * 512);
                half8 a1 = *(const half8*)(Ap + 16384 + kc * 512);
                #pragma unroll
                for (int nt = 0; nt < 8; ++nt) {
                    acc[0][nt] = __builtin_amdgcn_mfma_f32_16x16x32_f16(a0, wreg[nt][kc], acc[0][nt], 0, 0, 0);
                    acc[1][nt] = __builtin_amdgcn_mfma_f32_16x16x32_f16(a1, wreg[nt][kc], acc[1][nt], 0, 0, 0);
                }
            }
            // deposit partials (off critical path)
            #pragma unroll
            for (int mt = 0; mt < 2; ++mt)
                #pragma unroll
                for (int nt = 0; nt < 8; ++nt)
                    #pragma unroll
                    for (int r = 0; r < 4; ++r)
                        gplane[q][mt * 16 + quad * 4 + r]
                              [(nt >> 1) * 32 + (nt & 1) * 16 + nl] = acc[mt][nt][r];
        } else if (t > 0) {
            // ---- h-side: own-layer recurrence (the critical path) ----
            if (lane == 0) {
                const int tgt = GBLK * t;
                if (locok) {
                    const int* lp = &sy->loc[g][0];
                    int old, zero = 0;
                    for (;;) {
                        asm volatile("global_atomic_add %0, %1, %2, off sc0\n\t"
                                     "s_waitcnt vmcnt(0)"
                                     : "=v"(old) : "v"(lp), "v"(zero) : "memory");
                        if (old >= tgt) break;
                        __builtin_amdgcn_s_sleep(1);
                    }
                } else {
                    while (__hip_atomic_load(&sy->glb[g][0], __ATOMIC_RELAXED,
                                             __HIP_MEMORY_SCOPE_AGENT) < tgt)
                        __builtin_amdgcn_s_sleep(1);
                }
            }
            __builtin_amdgcn_sched_barrier(0);
            asm volatile("" ::: "memory");

            if (locok) {
                // asm sc0 loads: bypass L1, served by the group's XCD L2
                const _Float16* Ap = hloc + ((size_t)(g * 2) + ((t - 1) & 1)) * SLAB
                                   + (size_t)q * 4096 + (size_t)lane * 8;
                half8 areg[2][8];
                #pragma unroll
                for (int mt = 0; mt < 2; ++mt)
                    #pragma unroll
                    for (int kc = 0; kc < 8; ++kc)
                        asm volatile("global_load_dwordx4 %0, %1, off sc0"
                                     : "=v"(areg[mt][kc])
                                     : "v"(Ap + mt * 16384 + kc * 512));
                asm volatile("s_waitcnt vmcnt(0)" ::: "memory");
                __builtin_amdgcn_sched_barrier(0);
                #pragma unroll
                for (int kc = 0; kc < 8; ++kc)
                    #pragma unroll
                    for (int nt = 0; nt < 8; ++nt) {
                        acc[0][nt] = __builtin_amdgcn_mfma_f32_16x16x32_f16(areg[0][kc], wreg[nt][kc], acc[0][nt], 0, 0, 0);
                        acc[1][nt] = __builtin_amdgcn_mfma_f32_16x16x32_f16(areg[1][kc], wreg[nt][kc], acc[1][nt], 0, 0, 0);
                    }
            } else {
                // fallback: plain loads of write-once hfull (r4-r7 proven)
                const _Float16* Ap = hfull + hslot(t - 1, layer, team) * SLAB
                                   + (size_t)q * 4096 + (size_t)lane * 8;
                #pragma unroll
                for (int kc = 0; kc < 8; ++kc) {
                    half8 a0 = *(const half8*)(Ap + kc * 512);
                    half8 a1 = *(const half8*)(Ap + 16384 + kc * 512);
                    #pragma unroll
                    for (int nt = 0; nt < 8; ++nt) {
                        acc[0][nt] = __builtin_amdgcn_mfma_f32_16x16x32_f16(a0, wreg[nt][kc], acc[0][nt], 0, 0, 0);
                        acc[1][nt] = __builtin_amdgcn_mfma_f32_16x16x32_f16(a1, wreg[nt][kc], acc[1][nt], 0, 0, 0);
                    }
                }
            }
        }

        __syncthreads();   // bar1: x deposits complete
        if (kh == 1) {
            #pragma unroll
            for (int mt = 0; mt < 2; ++mt)
                #pragma unroll
                for (int nt = 0; nt < 8; ++nt)
                    #pragma unroll
                    for (int r = 0; r < 4; ++r)
                        gplane[q][mt * 16 + quad * 4 + r]
                              [(nt >> 1) * 32 + (nt & 1) * 16 + nl] += acc[mt][nt][r];
        }
        __syncthreads();   // bar2: reduction complete

        // ---- phase C: 512 threads, each (m, 2 cols) ----
        {
            const int m  = tid >> 4;            // 0..31
            const int jl = (tid & 15) * 2;      // 0..30

            f32x2 vi = *(const f32x2*)&gplane[0][m][0*32+jl] + *(const f32x2*)&gplane[1][m][0*32+jl]
                     + *(const f32x2*)&gplane[2][m][0*32+jl] + *(const f32x2*)&gplane[3][m][0*32+jl];
            f32x2 vf = *(const f32x2*)&gplane[0][m][1*32+jl] + *(const f32x2*)&gplane[1][m][1*32+jl]
                     + *(const f32x2*)&gplane[2][m][1*32+jl] + *(const f32x2*)&gplane[3][m][1*32+jl];
            f32x2 vg = *(const f32x2*)&gplane[0][m][2*32+jl] + *(const f32x2*)&gplane[1][m][2*32+jl]
                     + *(const f32x2*)&gplane[2][m][2*32+jl] + *(const f32x2*)&gplane[3][m][2*32+jl];
            f32x2 vo = *(const f32x2*)&gplane[0][m][3*32+jl] + *(const f32x2*)&gplane[1][m][3*32+jl]
                     + *(const f32x2*)&gplane[2][m][3*32+jl] + *(const f32x2*)&gplane[3][m][3*32+jl];

            f32x2 c = *(const f32x2*)&cbuf[m][jl];
            f32x2 cn, hn;
            #pragma unroll
            for (int i = 0; i < 2; ++i) {
                float gi = vi[i] + gbias[0][jl + i];
                float gf = vf[i] + gbias[1][jl + i];
                float gg = vg[i] + gbias[2][jl + i];
                float go = vo[i] + gbias[3][jl + i];
                cn[i] = sig_(gf) * c[i] + sig_(gi) * th_(gg);
                hn[i] = sig_(go) * th_(cn[i]);
            }
            *(f32x2*)&cbuf[m][jl] = cn;

            // h fragment offset: i = jblk, lane = (m&15) + ((jl>>3)&3)*16, idx = jl&7
            size_t off = ((size_t)(m >> 4) * 32 + jblk) * 512
                       + ((m & 15) + ((jl >> 3) & 3) * 16) * 8 + (jl & 7);
            half2v h2; h2[0] = (_Float16)hn[0]; h2[1] = (_Float16)hn[1];
            if (locok)
                *(half2v*)(hloc + ((size_t)(g * 2) + (t & 1)) * SLAB + off) = h2;  // plain -> local L2
            llc_store_h2(hfull + hslot(t, layer, team) * SLAB + off, h2);          // sc1 -> IF

            if (lastlayer && t == SEQ - 1)
                *(f32x2*)(out + (size_t)(team * 32 + m) * HID + j0 + jl) = hn;
        }

        asm volatile("s_waitcnt vmcnt(0)" ::: "memory");   // both store kinds acked
        __syncthreads();   // bar3: all waves drained; gplane reusable
        if (tid == 0) {
            if (locok) {
                const int* lp = &sy->loc[g][0];
                int one = 1;
                asm volatile("global_atomic_add %0, %1, off"
                             :: "v"(lp), "v"(one) : "memory");   // L2-local publish
            }
            __hip_atomic_fetch_add(&sy->glb[g][0], 1,
                                   __ATOMIC_RELAXED, __HIP_MEMORY_SCOPE_AGENT);
        }
    }
}

// ---------------------------------------------------------------------------
// Fallback: per-diagonal-step kernel (new geometry), used only if the
// cooperative enqueue fails. Kernel-boundary flushes make plain stores safe.
// ---------------------------------------------------------------------------
__global__ __launch_bounds__(512, 2) void k_step2(
        int s,
        const _Float16* __restrict__ xpack,
        const _Float16* __restrict__ wpack,
        const float*    __restrict__ bias,
        _Float16*       __restrict__ hfull,
        float*          __restrict__ cst,    // [NGRP][32][HID] f32
        float*          __restrict__ out)
{
    const int g     = blockIdx.x & 7;
    const int jblk  = blockIdx.x >> 3;
    const int layer = g >> 1;
    const int team  = g & 1;
    const int t = s - layer;
    if (t < 0 || t >= SEQ) return;
    const int j0    = jblk << 5;
    const int tid   = threadIdx.x;
    const int wave  = tid >> 6;
    const int q     = wave & 3;
    const int kh    = wave >> 2;
    const int lane  = tid & 63;
    const int nl    = lane & 15;
    const int quad  = lane >> 4;

    __shared__ __align__(16) float gplane[4][32][132];

    const _Float16* Wp = wpack
        + ((((size_t)(layer * 2 + kh) * 32 + jblk) * 4 + q) * 64) * 512
        + (size_t)lane * 8;

    f32x4 acc[2][8];
    #pragma unroll
    for (int mt = 0; mt < 2; ++mt)
        #pragma unroll
        for (int nt = 0; nt < 8; ++nt) acc[mt][nt] = (f32x4){0, 0, 0, 0};

    const bool active = (kh == 0) || (t > 0);
    if (active) {
        const _Float16* Ab;
        if (kh == 0) {
            Ab = (layer == 0) ? xpack + ((size_t)t * 2 + team) * SLAB
                              : hfull + hslot(t, layer - 1, team) * SLAB;
        } else {
            Ab = hfull + hslot(t - 1, layer, team) * SLAB;
        }
        const _Float16* Ap = Ab + (size_t)q * 4096 + (size_t)lane * 8;
        #pragma unroll
        for (int kc = 0; kc < 8; ++kc) {
            half8 a0 = *(const half8*)(Ap + kc * 512);
            half8 a1 = *(const half8*)(Ap + 16384 + kc * 512);
            #pragma unroll
            for (int nt = 0; nt < 8; ++nt) {
                half8 w = *(const half8*)(Wp + (nt * 8 + kc) * 512);
                acc[0][nt] = __builtin_amdgcn_mfma_f32_16x16x32_f16(a0, w, acc[0][nt], 0, 0, 0);
                acc[1][nt] = __builtin_amdgcn_mfma_f32_16x16x32_f16(a1, w, acc[1][nt], 0, 0, 0);
            }
        }
    }

    if (kh == 0) {
        #pragma unroll
        for (int mt = 0; mt < 2; ++mt)
            #pragma unroll
            for (int nt = 0; nt < 8; ++nt)
                #pragma unroll
                for (int r = 0; r < 4; ++r)
                    gplane[q][mt * 16 + quad * 4 + r]
                          [(nt >> 1) * 32 + (nt & 1) * 16 + nl] = acc[mt][nt][r];
    }
    __syncthreads();
    if (kh == 1) {
        #pragma unroll
        for (int mt = 0; mt < 2; ++mt)
            #pragma unroll
            for (int nt = 0; nt < 8; ++nt)
                #pragma unroll
                for (int r = 0; r < 4; ++r)
                    gplane[q][mt * 16 + quad * 4 + r]
                          [(nt >> 1) * 32 + (nt & 1) * 16 + nl] += acc[mt][nt][r];
    }
    __syncthreads();

    {
        const int m  = tid >> 4;
        const int jl = (tid & 15) * 2;
        f32x2 vi = *(const f32x2*)&gplane[0][m][0*32+jl] + *(const f32x2*)&gplane[1][m][0*32+jl]
                 + *(const f32x2*)&gplane[2][m][0*32+jl] + *(const f32x2*)&gplane[3][m][0*32+jl];
        f32x2 vf = *(const f32x2*)&gplane[0][m][1*32+jl] + *(const f32x2*)&gplane[1][m][1*32+jl]
                 + *(const f32x2*)&gplane[2][m][1*32+jl] + *(const f32x2*)&gplane[3][m][1*32+jl];
        f32x2 vg = *(const f32x2*)&gplane[0][m][2*32+jl] + *(const f32x2*)&gplane[1][m][2*32+jl]
                 + *(const f32x2*)&gplane[2][m][2*32+jl] + *(const f32x2*)&gplane[3][m][2*32+jl];
        f32x2 vo = *(const f32x2*)&gplane[0][m][3*32+jl] + *(const f32x2*)&gplane[1][m][3*32+jl]
                 + *(const f32x2*)&gplane[2][m][3*32+jl] + *(const f32x2*)&gplane[3][m][3*32+jl];

        const float* bb = bias + (size_t)layer * 4 * HID;
        float* cp = cst + ((size_t)g * 32 + m) * HID + j0 + jl;
        f32x2 c = *(const f32x2*)cp;
        f32x2 cn, hn;
        #pragma unroll
        for (int i = 0; i < 2; ++i) {
            float gi = vi[i] + bb[0 * HID + j0 + jl + i];
            float gf = vf[i] + bb[1 * HID + j0 + jl + i];
            float gg = vg[i] + bb[2 * HID + j0 + jl + i];
            float go = vo[i] + bb[3 * HID + j0 + jl + i];
            cn[i] = sig_(gf) * c[i] + sig_(gi) * th_(gg);
            hn[i] = sig_(go) * th_(cn[i]);
        }
        *(f32x2*)cp = cn;

        size_t off = ((size_t)(m >> 4) * 32 + jblk) * 512
                   + ((m & 15) + ((jl >> 3) & 3) * 16) * 8 + (jl & 7);
        half2v h2; h2[0] = (_Float16)hn[0]; h2[1] = (_Float16)hn[1];
        *(half2v*)(hfull + hslot(t, layer, team) * SLAB + off) = h2;

        if (layer == LAYERS - 1 && t == SEQ - 1)
            *(f32x2*)(out + (size_t)(team * 32 + m) * HID + j0 + jl) = hn;
    }
}

extern "C" void kernel_launch(void* const* d_in, const int* in_sizes, int n_in,
                              void* d_out, int out_size, void* d_ws, size_t ws_size,
                              hipStream_t stream) {
    const float* x32   = (const float*)d_in[0];
    const float* wih32 = (const float*)d_in[1];
    const float* whh32 = (const float*)d_in[2];
    const float* bih   = (const float*)d_in[3];
    const float* bhh   = (const float*)d_in[4];
    (void)in_sizes; (void)n_in; (void)out_size;

    char* ws = (char*)d_ws;
    size_t off = 0;
    float*    cst   = (float*)   (ws + off); off += (size_t)NGRP * 32 * HID * 4;          // 1 MB
    SyncSt*   sy    = (SyncSt*)  (ws + off); off += sizeof(SyncSt);
    off = (off + 255) & ~(size_t)255;
    size_t zero_bytes = off;                                   // cst + sync state
    float*    bias  = (float*)   (ws + off); off += (size_t)LAYERS * 4 * HID * 4;         // 64 KB
    _Float16* wpack = (_Float16*)(ws + off); off += (size_t)(1u << 22) * 8 * 2;           // 67 MB
    _Float16* xpack = (_Float16*)(ws + off); off += (size_t)(1u << 21) * 8 * 2;           // 33.5 MB
    _Float16* hloc  = (_Float16*)(ws + off); off += (size_t)NGRP * 2 * SLAB * 2;          // 1 MB
    _Float16* hfull = (_Float16*)(ws + off);
    size_t full_need = off + (size_t)(SEQ * LAYERS * 2 + 1) * SLAB * 2;                    // +128 MB
    const int can_persist = (ws_size >= full_need) ? 1 : 0;

    hipMemsetAsync(ws, 0, zero_bytes, stream);
    k_bias<<<(LAYERS * 4 * HID + 255) / 256, 256, 0, stream>>>(bih, bhh, bias);
    k_packw<<<(1u << 22) / 256, 256, 0, stream>>>(wih32, whh32, wpack);
    k_packx<<<(1u << 21) / 256, 256, 0, stream>>>(x32, xpack);

    hipError_t cerr = hipErrorUnknown;
    if (can_persist) {
        float* outp = (float*)d_out;
        _Float16* hfull_arg = hfull;
        _Float16* hloc_arg  = hloc;
        void* kargs[] = { (void*)&xpack, (void*)&wpack, (void*)&bih, (void*)&bhh,
                          (void*)&hfull_arg, (void*)&hloc_arg, (void*)&sy, (void*)&outp };
        cerr = hipLaunchCooperativeKernel(
            k_persist, dim3(NGRP * GBLK), dim3(512), kargs, 0u, stream);
    }

    if (cerr != hipSuccess && can_persist) {
        for (int s = 0; s < SEQ + LAYERS - 1; ++s)
            k_step2<<<NGRP * GBLK, 512, 0, stream>>>(
                s, xpack, wpack, bias, hfull, cst, (float*)d_out);
    }
}

// Round 9
// 2853.264 us; speedup vs baseline: 1.6431x; 1.6431x over previous
//
#include <hip/hip_runtime.h>

#define LAYERS 4
#define BATCH  64
#define SEQ    256
#define HID    1024

typedef _Float16 half8 __attribute__((ext_vector_type(8)));
typedef _Float16 half4 __attribute__((ext_vector_type(4)));
typedef float    f32x4 __attribute__((ext_vector_type(4)));
typedef unsigned long long u64;

__device__ __forceinline__ float sig_(float x) { return 1.0f / (1.0f + __expf(-x)); }
__device__ __forceinline__ float th_(float x)  { return 2.0f / (1.0f + __expf(-2.0f * x)) - 1.0f; }

// sc1 (LLC-coherent) store: relaxed agent-scope atomic -> write-through to the
// Infinity Cache (coherence point), bypassing the non-coherent per-XCD L2.
__device__ __forceinline__ void llc_store_h4(_Float16* p, half4 v) {
    union { half4 h; u64 u; } cv; cv.h = v;
    __hip_atomic_store((u64*)p, cv.u, __ATOMIC_RELAXED, __HIP_MEMORY_SCOPE_AGENT);
}

// Flag-slot sync: one word per block, flag[l][j] = number of steps block j of
// layer l has published. Producer: single sc1 store (no RMW, no tree).
// Consumer: one wave-wide coalesced load (lane i reads flag[l][i]) + __all.
struct BarSt {
    int flag[LAYERS][64];   // 256 B per layer, 4 cachelines
};

__global__ void k_bias(const float* __restrict__ bih, const float* __restrict__ bhh,
                       float* __restrict__ bias) {
    int i = blockIdx.x * blockDim.x + threadIdx.x;
    if (i < LAYERS * 4 * HID) bias[i] = bih[i] + bhh[i];
}

// Pack weights fp32 -> f16, gate-major per-wave fragment order.
__global__ void k_packw(const float* __restrict__ wih32, const float* __restrict__ whh32,
                        _Float16* __restrict__ wpack) {
    unsigned c = blockIdx.x * blockDim.x + threadIdx.x;   // < 2^22
    int lane = c & 63, g = (c >> 6) & 3, il = (c >> 8) & 7, q = (c >> 11) & 3;
    int jblk = (c >> 13) & 63, kh = (c >> 19) & 1, l = (int)(c >> 20);
    const float* src = (kh ? whh32 : wih32)
        + ((size_t)l * 4 * HID + (size_t)g * HID + jblk * 16 + (lane & 15)) * HID
        + (q * 8 + il) * 32 + (lane >> 4) * 8;
    f32x4 a = *(const f32x4*)src;
    f32x4 b = *(const f32x4*)(src + 4);
    half8 d;
    d[0]=(_Float16)a[0]; d[1]=(_Float16)a[1]; d[2]=(_Float16)a[2]; d[3]=(_Float16)a[3];
    d[4]=(_Float16)b[0]; d[5]=(_Float16)b[1]; d[6]=(_Float16)b[2]; d[7]=(_Float16)b[3];
    *(half8*)(wpack + (size_t)c * 8) = d;
}

// Pack x fp32 [B,T,H] -> f16 fragment order per t.
__global__ void k_packx(const float* __restrict__ x32, _Float16* __restrict__ xpack) {
    unsigned c = blockIdx.x * blockDim.x + threadIdx.x;   // < 2^21
    int lane = c & 63, i = (c >> 6) & 31, mt = (c >> 11) & 3, t = (int)(c >> 13);
    int m = mt * 16 + (lane & 15);
    int k = i * 32 + (lane >> 4) * 8;
    const float* src = x32 + ((size_t)m * SEQ + t) * HID + k;
    f32x4 a = *(const f32x4*)src;
    f32x4 b = *(const f32x4*)(src + 4);
    half8 d;
    d[0]=(_Float16)a[0]; d[1]=(_Float16)a[1]; d[2]=(_Float16)a[2]; d[3]=(_Float16)a[3];
    d[4]=(_Float16)b[0]; d[5]=(_Float16)b[1]; d[6]=(_Float16)b[2]; d[7]=(_Float16)b[3];
    *(half8*)(xpack + (size_t)c * 8) = d;
}

// ---------------------------------------------------------------------------
// Persistent kernel (r6 structure, flag-slot sync):
//  - weights in registers; c-state + bias in LDS; h slabs WRITE-ONCE
//    (hfull[t*L + l + 1], slot 0 = zeros); writers sc1-store (write-through to
//    IF), readers plain L2-cached 16B loads (no address written twice -> no
//    stale L2 line possible)
//  - BOTH m-halves deposited into a double reduction plane -> 3 barriers/step,
//    phase C on 256 threads
//  - sync: per-block flag store + wave-vectorized 64-slot poll (1 RTT each)
// 256 blocks (1/CU) x 512 threads: layer = bid>>6, 16 cols; wave = (kh, q).
// ---------------------------------------------------------------------------
__global__ __launch_bounds__(512, 1) void k_persist(
        const _Float16* __restrict__ xpack,
        const _Float16* __restrict__ wpack,
        const float*    __restrict__ bih,
        const float*    __restrict__ bhh,
        _Float16*       __restrict__ hfull,  // [SEQ*L+1][BH] f16, fragment order
        BarSt*          __restrict__ bar,
        float*          __restrict__ out)    // [B, H] fp32
{
    const int layer = blockIdx.x >> 6;
    const int jblk  = blockIdx.x & 63;
    const int j0    = jblk << 4;
    const int tid   = threadIdx.x;
    const int wave  = tid >> 6;
    const int q     = wave & 3;
    const int kh    = wave >> 2;
    const int lane  = tid & 63;
    const int nl    = lane & 15;
    const int quad  = lane >> 4;
    const size_t BH = (size_t)BATCH * HID;

    // double reduction plane: [m-half][q][g][row][pad20] = 80 KB, 2-way max
    __shared__ __align__(16) float gplane[2][4][4][32][20];
    __shared__ __align__(16) float cbuf[64][16];           // cell state
    __shared__ __align__(16) float gbias[4][16];           // bih+bhh slice

    for (int i = tid; i < 64 * 16; i += 512) ((float*)cbuf)[i] = 0.0f;
    if (tid < 64) {
        int g = tid >> 4, col = tid & 15;
        size_t bidx = (size_t)layer * 4 * HID + (size_t)g * HID + j0 + col;
        gbias[g][col] = bih[bidx] + bhh[bidx];
    }

    // weights -> registers, once (8 il x 4 gates x half8 = 128 regs/lane)
    const _Float16* Wp = wpack
        + ((((size_t)layer * 2 + kh) * 64 + jblk) * 4 + q) * 16384
        + (size_t)lane * 8;
    half8 wreg[8][4];
    #pragma unroll
    for (int il = 0; il < 8; ++il)
        #pragma unroll
        for (int g = 0; g < 4; ++g)
            wreg[il][g] = *(const half8*)(Wp + il * 2048 + g * 512);

    __syncthreads();

    const bool lastlayer = (layer == LAYERS - 1);

    for (int t = 0; t < SEQ; ++t) {
        // ---- wave-vectorized dataflow waits (one coalesced 64-slot load) ----
        if (kh == 0) {
            if (layer > 0) {
                const int tgt = t + 1;
                for (;;) {
                    int v = __hip_atomic_load(&bar->flag[layer - 1][lane],
                                              __ATOMIC_RELAXED, __HIP_MEMORY_SCOPE_AGENT);
                    if (__all(v >= tgt)) break;
                    __builtin_amdgcn_s_sleep(1);
                }
            }
        } else {
            if (t > 0) {
                const int tgt = t;
                for (;;) {
                    int v = __hip_atomic_load(&bar->flag[layer][lane],
                                              __ATOMIC_RELAXED, __HIP_MEMORY_SCOPE_AGENT);
                    if (__all(v >= tgt)) break;
                    __builtin_amdgcn_s_sleep(1);
                }
            }
        }
        __builtin_amdgcn_sched_barrier(0);
        asm volatile("" ::: "memory");

        // A operand base (fragment-packed), this wave's K-quarter
        const _Float16* Abase;
        if (kh == 0) {
            Abase = (layer == 0)
                ? (xpack + (size_t)t * BH)
                : (hfull + ((size_t)t * LAYERS + layer) * BH);       // (l-1, t)
        } else {
            Abase = hfull + (t == 0 ? (size_t)0
                                    : ((size_t)(t - 1) * LAYERS + layer + 1)) * BH;
        }
        const _Float16* Ap = Abase + (size_t)q * 4096 + (size_t)lane * 8;

        f32x4 acc[4][4];   // [mt][g]
        #pragma unroll
        for (int mt = 0; mt < 4; ++mt)
            #pragma unroll
            for (int g = 0; g < 4; ++g) acc[mt][g] = (f32x4){0,0,0,0};

        #pragma unroll
        for (int il = 0; il < 8; ++il) {
            #pragma unroll
            for (int mt = 0; mt < 4; ++mt) {
                half8 a = *(const half8*)(Ap + (size_t)mt * 16384 + il * 512);
                acc[mt][0] = __builtin_amdgcn_mfma_f32_16x16x32_f16(a, wreg[il][0], acc[mt][0], 0,0,0);
                acc[mt][1] = __builtin_amdgcn_mfma_f32_16x16x32_f16(a, wreg[il][1], acc[mt][1], 0,0,0);
                acc[mt][2] = __builtin_amdgcn_mfma_f32_16x16x32_f16(a, wreg[il][2], acc[mt][2], 0,0,0);
                acc[mt][3] = __builtin_amdgcn_mfma_f32_16x16x32_f16(a, wreg[il][3], acc[mt][3], 0,0,0);
            }
        }

        _Float16* hp = hfull + ((size_t)t * LAYERS + layer + 1) * BH;
        const bool last = lastlayer && (t == SEQ - 1);

        // phase A: kh=1 waves deposit BOTH halves
        if (kh == 1) {
            #pragma unroll
            for (int mt = 0; mt < 4; ++mt)
                #pragma unroll
                for (int g = 0; g < 4; ++g)
                    #pragma unroll
                    for (int r = 0; r < 4; ++r) {
                        int rm = mt * 16 + quad * 4 + r;   // 0..63
                        gplane[rm >> 5][q][g][rm & 31][nl] = acc[mt][g][r];
                    }
        }
        __syncthreads();
        // phase B: kh=0 waves add theirs (both halves)
        if (kh == 0) {
            #pragma unroll
            for (int mt = 0; mt < 4; ++mt)
                #pragma unroll
                for (int g = 0; g < 4; ++g)
                    #pragma unroll
                    for (int r = 0; r < 4; ++r) {
                        int rm = mt * 16 + quad * 4 + r;
                        gplane[rm >> 5][q][g][rm & 31][nl] += acc[mt][g][r];
                    }
        }
        __syncthreads();
        // phase C: 256 threads, each one (m, 4-col group): combine q-partials,
        // LSTM cell, write h (fragment order)
        if (tid < 256) {
            const int m  = tid >> 2;          // 0..63
            const int hb = m >> 5;
            const int ml = m & 31;
            const int jg = tid & 3;
            const int jA = j0 + jg * 4;

            f32x4 vi = *(const f32x4*)&gplane[hb][0][0][ml][jg*4] + *(const f32x4*)&gplane[hb][1][0][ml][jg*4]
                     + *(const f32x4*)&gplane[hb][2][0][ml][jg*4] + *(const f32x4*)&gplane[hb][3][0][ml][jg*4];
            f32x4 vf = *(const f32x4*)&gplane[hb][0][1][ml][jg*4] + *(const f32x4*)&gplane[hb][1][1][ml][jg*4]
                     + *(const f32x4*)&gplane[hb][2][1][ml][jg*4] + *(const f32x4*)&gplane[hb][3][1][ml][jg*4];
            f32x4 vg = *(const f32x4*)&gplane[hb][0][2][ml][jg*4] + *(const f32x4*)&gplane[hb][1][2][ml][jg*4]
                     + *(const f32x4*)&gplane[hb][2][2][ml][jg*4] + *(const f32x4*)&gplane[hb][3][2][ml][jg*4];
            f32x4 vo = *(const f32x4*)&gplane[hb][0][3][ml][jg*4] + *(const f32x4*)&gplane[hb][1][3][ml][jg*4]
                     + *(const f32x4*)&gplane[hb][2][3][ml][jg*4] + *(const f32x4*)&gplane[hb][3][3][ml][jg*4];

            f32x4 bi = *(const f32x4*)&gbias[0][jg*4];
            f32x4 bf = *(const f32x4*)&gbias[1][jg*4];
            f32x4 bg = *(const f32x4*)&gbias[2][jg*4];
            f32x4 bo = *(const f32x4*)&gbias[3][jg*4];

            f32x4 c = *(const f32x4*)&cbuf[m][jg*4];
            f32x4 cn, hn;
            #pragma unroll
            for (int i = 0; i < 4; ++i) {
                float gi = vi[i] + bi[i];
                float gf = vf[i] + bf[i];
                float gg = vg[i] + bg[i];
                float go = vo[i] + bo[i];
                cn[i] = sig_(gf) * c[i] + sig_(gi) * th_(gg);
                hn[i] = sig_(go) * th_(cn[i]);
            }
            *(f32x4*)&cbuf[m][jg*4] = cn;

            int i_ = jA >> 5, qd = (jA >> 3) & 3, jj = jA & 7;
            size_t hoff = (size_t)(m >> 4) * 16384 + (size_t)i_ * 512 + qd * 128 + (m & 15) * 8 + jj;
            half4 h4;
            h4[0]=(_Float16)hn[0]; h4[1]=(_Float16)hn[1]; h4[2]=(_Float16)hn[2]; h4[3]=(_Float16)hn[3];
            llc_store_h4(hp + hoff, h4);   // write-through to IF (sc1)

            if (last) *(f32x4*)(out + (size_t)m * HID + jA) = hn;
        }

        // ---- end of step: drain h stores, then single-store publish ----
        asm volatile("s_waitcnt vmcnt(0)" ::: "memory");   // sc1 stores acked at IF
        __syncthreads();                                    // also guards gplane reuse
        if (tid == 0)
            __hip_atomic_store(&bar->flag[layer][jblk], t + 1,
                               __ATOMIC_RELAXED, __HIP_MEMORY_SCOPE_AGENT);
    }
}

// ---------------------------------------------------------------------------
// Fallback: proven per-step kernel, used only if cooperative enqueue fails
// or the workspace is too small for write-once slabs.
// ---------------------------------------------------------------------------
__global__ __launch_bounds__(512) void k_step(
        int s,
        const _Float16* __restrict__ xpack,
        const _Float16* __restrict__ wpack,
        const float*    __restrict__ bias,
        _Float16*       __restrict__ hbuf,
        float*          __restrict__ cst,
        float*          __restrict__ out)
{
    const int layer = blockIdx.x >> 6;
    const int t = s - layer;
    if (t < 0 || t >= SEQ) return;

    __shared__ __align__(16) float gplane[4][4][32][16];

    const int tid  = threadIdx.x;
    const int wave = tid >> 6;
    const int q    = wave & 3;
    const int kh   = wave >> 2;
    const int lane = tid & 63;
    const int nl   = lane & 15;
    const int quad = lane >> 4;
    const int jblk = blockIdx.x & 63;
    const int j0   = jblk << 4;
    const size_t BH = (size_t)BATCH * HID;

    const _Float16* Abase;
    if (kh == 0) {
        Abase = (layer == 0) ? (xpack + (size_t)t * BH)
                             : (hbuf + ((size_t)(layer - 1) * 2 + (t & 1)) * BH);
    } else {
        Abase = hbuf + ((size_t)layer * 2 + ((t + 1) & 1)) * BH;
    }
    const _Float16* Ap = Abase + (size_t)q * 4096 + (size_t)lane * 8;
    const _Float16* Wp = wpack
        + ((((size_t)layer * 2 + kh) * 64 + jblk) * 4 + q) * 16384
        + (size_t)lane * 8;

    f32x4 acc[4][4];
    #pragma unroll
    for (int mt = 0; mt < 4; ++mt)
        #pragma unroll
        for (int g = 0; g < 4; ++g) acc[mt][g] = (f32x4){0,0,0,0};

    #pragma unroll
    for (int il = 0; il < 8; ++il) {
        half8 w0 = *(const half8*)(Wp + il * 2048 + 0 * 512);
        half8 w1 = *(const half8*)(Wp + il * 2048 + 1 * 512);
        half8 w2 = *(const half8*)(Wp + il * 2048 + 2 * 512);
        half8 w3 = *(const half8*)(Wp + il * 2048 + 3 * 512);
        #pragma unroll
        for (int mt = 0; mt < 4; ++mt) {
            half8 a = *(const half8*)(Ap + (size_t)mt * 16384 + il * 512);
            acc[mt][0] = __builtin_amdgcn_mfma_f32_16x16x32_f16(a, w0, acc[mt][0], 0,0,0);
            acc[mt][1] = __builtin_amdgcn_mfma_f32_16x16x32_f16(a, w1, acc[mt][1], 0,0,0);
            acc[mt][2] = __builtin_amdgcn_mfma_f32_16x16x32_f16(a, w2, acc[mt][2], 0,0,0);
            acc[mt][3] = __builtin_amdgcn_mfma_f32_16x16x32_f16(a, w3, acc[mt][3], 0,0,0);
        }
    }

    const float* bb = bias + (size_t)layer * 4 * HID;
    _Float16* hp = hbuf + ((size_t)layer * 2 + (t & 1)) * BH;
    const bool last = (layer == LAYERS - 1) && (t == SEQ - 1);

    #pragma unroll
    for (int half = 0; half < 2; ++half) {
        if (kh == 1) {
            #pragma unroll
            for (int mtl = 0; mtl < 2; ++mtl)
                #pragma unroll
                for (int g = 0; g < 4; ++g)
                    #pragma unroll
                    for (int r = 0; r < 4; ++r)
                        gplane[q][g][mtl * 16 + quad * 4 + r][nl] = acc[half * 2 + mtl][g][r];
        }
        __syncthreads();
        if (kh == 0) {
            #pragma unroll
            for (int mtl = 0; mtl < 2; ++mtl)
                #pragma unroll
                for (int g = 0; g < 4; ++g)
                    #pragma unroll
                    for (int r = 0; r < 4; ++r)
                        gplane[q][g][mtl * 16 + quad * 4 + r][nl] += acc[half * 2 + mtl][g][r];
        }
        __syncthreads();
        if (tid < 128) {
            const int ml = tid >> 2;
            const int jg = tid & 3;
            const int m  = half * 32 + ml;
            const int jA = j0 + jg * 4;

            f32x4 vi = *(const f32x4*)&gplane[0][0][ml][jg*4] + *(const f32x4*)&gplane[1][0][ml][jg*4]
                     + *(const f32x4*)&gplane[2][0][ml][jg*4] + *(const f32x4*)&gplane[3][0][ml][jg*4];
            f32x4 vf = *(const f32x4*)&gplane[0][1][ml][jg*4] + *(const f32x4*)&gplane[1][1][ml][jg*4]
                     + *(const f32x4*)&gplane[2][1][ml][jg*4] + *(const f32x4*)&gplane[3][1][ml][jg*4];
            f32x4 vg = *(const f32x4*)&gplane[0][2][ml][jg*4] + *(const f32x4*)&gplane[1][2][ml][jg*4]
                     + *(const f32x4*)&gplane[2][2][ml][jg*4] + *(const f32x4*)&gplane[3][2][ml][jg*4];
            f32x4 vo = *(const f32x4*)&gplane[0][3][ml][jg*4] + *(const f32x4*)&gplane[1][3][ml][jg*4]
                     + *(const f32x4*)&gplane[2][3][ml][jg*4] + *(const f32x4*)&gplane[3][3][ml][jg*4];

            f32x4 bi = *(const f32x4*)(bb + 0 * HID + jA);
            f32x4 bf = *(const f32x4*)(bb + 1 * HID + jA);
            f32x4 bg = *(const f32x4*)(bb + 2 * HID + jA);
            f32x4 bo = *(const f32x4*)(bb + 3 * HID + jA);

            float* cp = cst + (size_t)layer * BH + (size_t)m * HID + jA;
            f32x4 c = *(const f32x4*)cp;
            f32x4 cn, hn;
            #pragma unroll
            for (int i = 0; i < 4; ++i) {
                float gi = vi[i] + bi[i];
                float gf = vf[i] + bf[i];
                float gg = vg[i] + bg[i];
                float go = vo[i] + bo[i];
                cn[i] = sig_(gf) * c[i] + sig_(gi) * th_(gg);
                hn[i] = sig_(go) * th_(cn[i]);
            }
            *(f32x4*)cp = cn;

            int i_ = jA >> 5, qd = (jA >> 3) & 3, jj = jA & 7;
            size_t hoff = (size_t)(m >> 4) * 16384 + (size_t)i_ * 512 + qd * 128 + (m & 15) * 8 + jj;
            half4 h4;
            h4[0]=(_Float16)hn[0]; h4[1]=(_Float16)hn[1]; h4[2]=(_Float16)hn[2]; h4[3]=(_Float16)hn[3];
            *(half4*)(hp + hoff) = h4;

            if (last) *(f32x4*)(out + (size_t)m * HID + jA) = hn;
        }
        __syncthreads();
    }
}

extern "C" void kernel_launch(void* const* d_in, const int* in_sizes, int n_in,
                              void* d_out, int out_size, void* d_ws, size_t ws_size,
                              hipStream_t stream) {
    const float* x32   = (const float*)d_in[0];
    const float* wih32 = (const float*)d_in[1];
    const float* whh32 = (const float*)d_in[2];
    const float* bih   = (const float*)d_in[3];
    const float* bhh   = (const float*)d_in[4];
    (void)in_sizes; (void)n_in; (void)out_size;

    const size_t BH = (size_t)BATCH * HID;
    char* ws = (char*)d_ws;
    size_t off = 0;
    _Float16* hpar  = (_Float16*)(ws + off); off += (size_t)LAYERS * 2 * BH * 2;      // 1 MB (fallback)
    float*    cst   = (float*)   (ws + off); off += (size_t)LAYERS * BH * 4;          // 1 MB (fallback)
    BarSt*    bar   = (BarSt*)   (ws + off); off += sizeof(BarSt);
    off = (off + 255) & ~(size_t)255;
    size_t zero_bytes = off;                      // hpar + cst + sync flags
    float*    bias  = (float*)   (ws + off); off += (size_t)LAYERS * 4 * HID * 4;     // 64 KB
    _Float16* wpack = (_Float16*)(ws + off); off += (size_t)2 * LAYERS * 4 * HID * HID * 2; // 67 MB
    _Float16* xpack = (_Float16*)(ws + off); off += (size_t)SEQ * BH * 2;             // 33.5 MB
    _Float16* hfull = (_Float16*)(ws + off);
    size_t full_need = off + (size_t)(SEQ * LAYERS + 1) * BH * 2;                      // +131 MB
    const int can_persist = (ws_size >= full_need) ? 1 : 0;

    hipMemsetAsync(ws, 0, zero_bytes, stream);
    if (can_persist) hipMemsetAsync(hfull, 0, BH * 2, stream);  // zero slab 0 (t=-1 state)
    k_bias<<<(LAYERS * 4 * HID + 255) / 256, 256, 0, stream>>>(bih, bhh, bias);
    k_packw<<<(1u << 22) / 256, 256, 0, stream>>>(wih32, whh32, wpack);
    k_packx<<<(1u << 21) / 256, 256, 0, stream>>>(x32, xpack);

    hipError_t cerr = hipErrorUnknown;
    if (can_persist) {
        float* outp = (float*)d_out;
        _Float16* hfull_arg = hfull;
        void* kargs[] = { (void*)&xpack, (void*)&wpack, (void*)&bih, (void*)&bhh,
                          (void*)&hfull_arg, (void*)&bar, (void*)&outp };
        cerr = hipLaunchCooperativeKernel(
            k_persist, dim3(LAYERS * 64), dim3(512), kargs, 0u, stream);
    }

    if (cerr != hipSuccess) {
        for (int s = 0; s < SEQ + LAYERS - 1; ++s)
            k_step<<<LAYERS * 64, 512, 0, stream>>>(
                s, xpack, wpack, bias, hpar, cst, (float*)d_out);
    }
}